// Round 1
// 497.381 us; speedup vs baseline: 1.0063x; 1.0063x over previous
//
#include <hip/hip_runtime.h>
#include <math.h>

// Fused pool+combine, single pass, zero workspace traffic.
//
// Problem geometry (fixed by reference):
//   in1: (8,256, 64, 64)  pool k=2  -> p1 (8,256,32,32)
//   in2: (8,128,128,128)  pool k=4  -> p2 (8,128,32,32)
//   in3: (8, 64,256,256)  pool k=8  -> p3 (8, 64,32,32)
//   in4: (8, 32,512,512)  pool k=16 -> p4 (8, 32,32,32)
//   out[b,c,h,w] = relu(ff[b,c,h,w] + p1[b,c%256,h,w] + p2[b,c%128,h,w]
//                       + p3[b,c%64,h,w] + p4[b,c%32,h,w])
//
// Key observation: the channel-tiling means output channel group
// {c : c % 32 == m} (16 channels) needs exactly:
//   p4 channel m, p3 channels {m,m+32}, p2 {m,m+32,m+64,m+96},
//   p1 {m+32j, j=0..7}.
// That entire reuse set for an 8-row band is only 15 KB pooled -> fits LDS.
// So one block = (b, m, row-quadrant s): pool into LDS, barrier,
// sum+relu+store. Every input byte is read exactly ONCE globally, and the
// 31 MB workspace round trip + second launch disappear.
//
// Grid: 8 * 32 * 4 = 1024 blocks x 256 threads. All blocks do identical
// work (496 KB read each); no inter-block data sharing at all.

__device__ __forceinline__ float max4(float4 v) {
    return fmaxf(fmaxf(v.x, v.y), fmaxf(v.z, v.w));
}

__global__ __launch_bounds__(256, 4) void fused_kernel(
    const float* __restrict__ in1, const float* __restrict__ in2,
    const float* __restrict__ in3, const float* __restrict__ in4,
    const float* __restrict__ ff, float* __restrict__ out) {

    // Pooled tiles for this block's 8-row band (15 KB total).
    __shared__ float p4s[8][32];        //  1 KB, channel m
    __shared__ float p3s[2][8][32];     //  2 KB, channels m+32j
    __shared__ float p2s[4][8][32];     //  4 KB
    __shared__ float p1s[8][8][32];     //  8 KB

    const int tid = threadIdx.x;
    const int bid = blockIdx.x;
    const int s   = bid & 3;            // row quadrant: oh in [8s, 8s+8)
    const int m   = (bid >> 2) & 31;    // channel mod 32
    const int b   = bid >> 7;           // batch

    const int col = tid & 31;           // pooled col 0..31
    const int row = tid >> 5;           // 0..7 within band
    const int oh  = s * 8 + row;        // pooled row 0..31

    // ---- pool in4 (k=16, W=512), channel m: 1 px/thread (64 x float4) ----
    {
        const float* p = in4 + ((size_t)(b * 32 + m) * 512 + oh * 16) * 512
                             + col * 16;
        float mx = -INFINITY;
#pragma unroll 4
        for (int r = 0; r < 16; ++r) {
#pragma unroll
            for (int c = 0; c < 16; c += 4)
                mx = fmaxf(mx, max4(*(const float4*)(p + r * 512 + c)));
        }
        p4s[row][col] = mx;
    }

    // ---- pool in3 (k=8, W=256), channels m, m+32: 2 px/thread ----
#pragma unroll
    for (int j = 0; j < 2; ++j) {
        const float* p = in3 + ((size_t)(b * 64 + m + 32 * j) * 256 + oh * 8) * 256
                             + col * 8;
        float mx = -INFINITY;
#pragma unroll
        for (int r = 0; r < 8; ++r) {
            mx = fmaxf(mx, max4(*(const float4*)(p + r * 256)));
            mx = fmaxf(mx, max4(*(const float4*)(p + r * 256 + 4)));
        }
        p3s[j][row][col] = mx;
    }

    // ---- pool in2 (k=4, W=128), channels m+32j, j=0..3 ----
#pragma unroll
    for (int j = 0; j < 4; ++j) {
        const float* p = in2 + ((size_t)(b * 128 + m + 32 * j) * 128 + oh * 4) * 128
                             + col * 4;
        float mx = -INFINITY;
#pragma unroll
        for (int r = 0; r < 4; ++r)
            mx = fmaxf(mx, max4(*(const float4*)(p + r * 128)));
        p2s[j][row][col] = mx;
    }

    // ---- pool in1 (k=2, W=64), channels m+32j, j=0..7 ----
#pragma unroll
    for (int j = 0; j < 8; ++j) {
        const float* p = in1 + ((size_t)(b * 256 + m + 32 * j) * 64 + oh * 2) * 64
                             + col * 2;
        float2 v0 = *(const float2*)p;
        float2 v1 = *(const float2*)(p + 64);
        p1s[j][row][col] = fmaxf(fmaxf(v0.x, v0.y), fmaxf(v1.x, v1.y));
    }

    __syncthreads();

    // ---- combine + relu + store: 16 channels x 8 rows x 32 cols ----
    // One wave per channel per pass (64 lanes = 64 contiguous float4 = the
    // whole 8x32 band of one channel). 4 passes cover 16 channels.
    const int ci  = tid >> 6;           // wave id 0..3 = channel-within-pass
    const int idx = tid & 63;           // lane
    const int r2  = idx >> 3;           // row 0..7
    const int q   = idx & 7;            // float4 col 0..7
#pragma unroll
    for (int pass = 0; pass < 4; ++pass) {
        const int i = pass * 4 + ci;                    // 0..15
        const int c = m + 32 * i;                       // output channel
        const size_t o4 = (size_t)(b * 512 + c) * 256 + (s * 8 + r2) * 8 + q;
        float4 a  = ((const float4*)ff)[o4];
        float4 v1 = *(const float4*)&p1s[i & 7][r2][q * 4];
        float4 v2 = *(const float4*)&p2s[i & 3][r2][q * 4];
        float4 v3 = *(const float4*)&p3s[i & 1][r2][q * 4];
        float4 v4 = *(const float4*)&p4s[r2][q * 4];
        float4 o;
        o.x = fmaxf(a.x + v1.x + v2.x + v3.x + v4.x, 0.0f);
        o.y = fmaxf(a.y + v1.y + v2.y + v3.y + v4.y, 0.0f);
        o.z = fmaxf(a.z + v1.z + v2.z + v3.z + v4.z, 0.0f);
        o.w = fmaxf(a.w + v1.w + v2.w + v3.w + v4.w, 0.0f);
        ((float4*)out)[o4] = o;
    }
}

extern "C" void kernel_launch(void* const* d_in, const int* in_sizes, int n_in,
                              void* d_out, int out_size, void* d_ws, size_t ws_size,
                              hipStream_t stream) {
    const float* in1 = (const float*)d_in[0];
    const float* in2 = (const float*)d_in[1];
    const float* in3 = (const float*)d_in[2];
    const float* in4 = (const float*)d_in[3];
    const float* ff  = (const float*)d_in[4];
    float* out = (float*)d_out;
    (void)d_ws; (void)ws_size;

    fused_kernel<<<1024, 256, 0, stream>>>(in1, in2, in3, in4, ff, out);
}